// Round 10
// baseline (444.676 us; speedup 1.0000x reference)
//
#include <hip/hip_runtime.h>
#include <hip/hip_fp16.h>

// GCN, 7 layers: h = relu(Â (h W) + b), Â = D^-1/2 (A + I) D^-1/2.
// Round 25: degree-sorted node permutation for the aggregations.
//  Evidence: r24's ILP 4->8 gave -23.6us => aggs are latency-bound with
//  insufficient TLP (TLP-absorbed stalls wouldn't respond to per-lane ILP).
//  Next quantified waste: intra-wave degree divergence — a wave covers
//  8/16/32/64 nodes (F=50/30/10/1) and runs max_i ceil(d_i/8) batches while
//  only avg are useful: ~25% wasted slots at F=50, ~45% F=30, ~50% F=10,
//  ~2x in agg1. Fix: process nodes in degree-sorted order (perm[]) so waves
//  get similar-degree nodes (max ~= avg). Sort = 4 tiny kernels (64 bins,
//  bucket-major hist/scan/place — the same proven pattern as the CSR build,
//  LDS atomics only, ~6-10us). Agg bodies unchanged except g = perm[gidx];
//  per-node arithmetic identical => absmax bitwise unchanged.
//  Everything else byte-identical to round 24 (418.4us measured).

static constexpr int NN = 100000;
static constexpr int NE = 1600000;
static constexpr int BKL = 9;                      // 512 nodes per bucket
static constexpr int NBUK = (NN + 511) >> BKL;     // 196 buckets
static constexpr int EPT = 8;                      // edges per thread (hist/A1)
static constexpr int EB = (NE + 2047) / 2048;      // 782 edge blocks
static constexpr int SNB = (NN + 255) / 256;       // 391 node blocks (sort)

// ---------------- 1. bucket histogram (LDS only) ----------------

__global__ __launch_bounds__(256) void k_hist0(const int* __restrict__ col,
                                               int* __restrict__ counts) {
    __shared__ int lh[NBUK];
    for (int j = threadIdx.x; j < NBUK; j += 256) lh[j] = 0;
    __syncthreads();
    int base = blockIdx.x * 2048;
#pragma unroll
    for (int k = 0; k < EPT; ++k) {
        int e = base + k * 256 + threadIdx.x;
        if (e < NE) atomicAdd(&lh[col[e] >> BKL], 1);
    }
    __syncthreads();
    for (int j = threadIdx.x; j < NBUK; j += 256)
        counts[j * EB + blockIdx.x] = lh[j];  // bucket-major
}

// ---------------- 2a. per-bucket scan (196 parallel blocks) ----------------

__global__ __launch_bounds__(256) void k_scanA(int* __restrict__ counts,
                                               int* __restrict__ btot) {
    __shared__ int lds[256];
    const int b = blockIdx.x;
    const int t = threadIdx.x;
    int* c = counts + (size_t)b * EB;
    constexpr int PER = (EB + 255) / 256;  // 4
    int v[PER];
    int s = 0;
#pragma unroll
    for (int k = 0; k < PER; ++k) {
        int idx = t * PER + k;
        v[k] = (idx < EB) ? c[idx] : 0;
        s += v[k];
    }
    lds[t] = s;
    __syncthreads();
    for (int off = 1; off < 256; off <<= 1) {
        int u = (t >= off) ? lds[t - off] : 0;
        __syncthreads();
        lds[t] += u;
        __syncthreads();
    }
    int run = lds[t] - s;
#pragma unroll
    for (int k = 0; k < PER; ++k) {
        int idx = t * PER + k;
        if (idx < EB) { c[idx] = run; run += v[k]; }
    }
    if (t == 255) btot[b] = lds[255];
}

// ---------------- 2b. scan of 196 bucket totals -> bstart ----------------

__global__ void k_scanB(const int* __restrict__ btot, int* __restrict__ bstart) {
    __shared__ int lds[256];
    int t = threadIdx.x;
    int v = (t < NBUK) ? btot[t] : 0;
    lds[t] = v;
    __syncthreads();
    for (int off = 1; off < 256; off <<= 1) {
        int u = (t >= off) ? lds[t - off] : 0;
        __syncthreads();
        lds[t] += u;
        __syncthreads();
    }
    if (t < NBUK) bstart[t] = lds[t] - v;  // exclusive
    if (t == 0) bstart[NBUK] = NE;
}

// ---------------- 3. stage records, bucket-grouped (LDS cursors) ----------

__global__ __launch_bounds__(256) void k_A1(const int* __restrict__ row,
                                            const int* __restrict__ col,
                                            const float* __restrict__ ew,
                                            const int* __restrict__ counts,
                                            const int* __restrict__ bstart,
                                            int2* __restrict__ stg) {
    __shared__ int cur[NBUK];
    for (int j = threadIdx.x; j < NBUK; j += 256)
        cur[j] = bstart[j] + counts[j * EB + blockIdx.x];
    __syncthreads();
    int base = blockIdx.x * 2048;
#pragma unroll
    for (int k = 0; k < EPT; ++k) {
        int e = base + k * 256 + threadIdx.x;
        if (e < NE) {
            int c = col[e], r = row[e];
            int pos = atomicAdd(&cur[c >> BKL], 1);  // LDS atomic
            stg[pos] = make_int2(((c & 511) << 17) | r, __float_as_int(ew[e]));
        }
    }
}

// ---------------- 4. per-bucket degree -> dinv (plain stores) ----------

__global__ __launch_bounds__(256) void k_bdeg(const int* __restrict__ bstart,
                                              const int2* __restrict__ stg,
                                              float* __restrict__ dinv) {
    __shared__ float sdeg[512];
    const int b = blockIdx.x;
    for (int j = threadIdx.x; j < 512; j += 256) sdeg[j] = 0.0f;
    __syncthreads();
    const int s = bstart[b], e = bstart[b + 1];
    for (int p = s + threadIdx.x; p < e; p += 256) {
        int2 rec = stg[p];
        atomicAdd(&sdeg[rec.x >> 17], __int_as_float(rec.y));
    }
    __syncthreads();
    for (int j = threadIdx.x; j < 512; j += 256) {
        int idx = (b << BKL) + j;
        if (idx < NN) dinv[idx] = rsqrtf(sdeg[j] + 1.0f);  // +1 self-loop
    }
}

// ---------------- 5. per-bucket placement: offs + csw (LDS scan) ----------

__global__ __launch_bounds__(512) void k_place(const int* __restrict__ bstart,
                                               const int2* __restrict__ stg,
                                               const float* __restrict__ dinv,
                                               int* __restrict__ offs,
                                               int2* __restrict__ csw) {
    __shared__ int lcnt[512];
    __shared__ int cur[512];
    const int b = blockIdx.x;
    const int t = threadIdx.x;
    lcnt[t] = 0;
    __syncthreads();
    const int s = bstart[b], e = bstart[b + 1];
    for (int p = s + t; p < e; p += 512)
        atomicAdd(&lcnt[stg[p].x >> 17], 1);
    __syncthreads();
    int v = lcnt[t];
    for (int off = 1; off < 512; off <<= 1) {   // inclusive Hillis-Steele
        int u = (t >= off) ? lcnt[t - off] : 0;
        __syncthreads();
        lcnt[t] += u;
        __syncthreads();
    }
    int excl = lcnt[t] - v;
    int idx = (b << BKL) + t;
    if (idx <= NN) offs[idx] = s + excl;        // covers offs[NN] exactly once
    cur[t] = s + excl;
    __syncthreads();
    for (int p = s + t; p < e; p += 512) {
        int2 rec = stg[p];
        int cl = rec.x >> 17;
        int r = rec.x & 0x1FFFF;
        float nw = dinv[r] * __int_as_float(rec.y) * dinv[(b << BKL) + cl];
        int slot = atomicAdd(&cur[cl], 1);      // LDS atomic
        csw[slot] = make_int2(r, __float_as_int(nw));
    }
}

// ---------------- 5b. degree sort: perm[] (64 bins, bucket-major) ---------

__global__ __launch_bounds__(256) void k_shist(const int* __restrict__ offs,
                                               int* __restrict__ scnt) {
    __shared__ int lh[64];
    const int t = threadIdx.x;
    if (t < 64) lh[t] = 0;
    __syncthreads();
    const int g = blockIdx.x * 256 + t;
    if (g < NN) {
        int d = offs[g + 1] - offs[g];
        atomicAdd(&lh[min(d, 63)], 1);
    }
    __syncthreads();
    if (t < 64) scnt[t * SNB + blockIdx.x] = lh[t];
}

__global__ __launch_bounds__(256) void k_sscanA(int* __restrict__ scnt,
                                                int* __restrict__ stot) {
    __shared__ int lds[256];
    const int b = blockIdx.x;       // bin
    const int t = threadIdx.x;
    int* c = scnt + (size_t)b * SNB;
    constexpr int PER = (SNB + 255) / 256;  // 2
    int v[PER];
    int s = 0;
#pragma unroll
    for (int k = 0; k < PER; ++k) {
        int idx = t * PER + k;
        v[k] = (idx < SNB) ? c[idx] : 0;
        s += v[k];
    }
    lds[t] = s;
    __syncthreads();
    for (int off = 1; off < 256; off <<= 1) {
        int u = (t >= off) ? lds[t - off] : 0;
        __syncthreads();
        lds[t] += u;
        __syncthreads();
    }
    int run = lds[t] - s;
#pragma unroll
    for (int k = 0; k < PER; ++k) {
        int idx = t * PER + k;
        if (idx < SNB) { c[idx] = run; run += v[k]; }
    }
    if (t == 255) stot[b] = lds[255];
}

__global__ void k_sscanB(const int* __restrict__ stot, int* __restrict__ sbst) {
    __shared__ int lds[64];
    int t = threadIdx.x;            // launched with 64 threads
    int v = stot[t];
    lds[t] = v;
    __syncthreads();
    for (int off = 1; off < 64; off <<= 1) {
        int u = (t >= off) ? lds[t - off] : 0;
        __syncthreads();
        lds[t] += u;
        __syncthreads();
    }
    sbst[t] = lds[t] - v;           // exclusive bin start
}

__global__ __launch_bounds__(256) void k_splace(const int* __restrict__ offs,
                                                const int* __restrict__ scnt,
                                                const int* __restrict__ sbst,
                                                int* __restrict__ perm) {
    __shared__ int cur[64];
    const int t = threadIdx.x;
    if (t < 64) cur[t] = sbst[t] + scnt[t * SNB + blockIdx.x];
    __syncthreads();
    const int g = blockIdx.x * 256 + t;
    if (g < NN) {
        int d = offs[g + 1] - offs[g];
        int pos = atomicAdd(&cur[min(d, 63)], 1);   // LDS atomic
        perm[pos] = g;
    }
}

// ---------------- weight prep (6 small blocks, runs once per graph) -------

typedef short s16x8 __attribute__((ext_vector_type(8)));
typedef float f32x4v __attribute__((ext_vector_type(4)));
typedef _Float16 f16x8 __attribute__((ext_vector_type(8)));

static __device__ __forceinline__ unsigned short bf16rn(float f) {
    unsigned u = __float_as_uint(f);
    return (unsigned short)((u + 0x7FFFu + ((u >> 16) & 1u)) >> 16);
}

// wt layout (shorts):
//  [0, 16384)      layer-1 bf16 hi|lo, transposed, XOR-swizzled (round-22)
//  [WT2..) fp16 hi|lo transposed tiles, pitch-padded, for layers 2..5
static constexpr int WT2 = 16384;                  // 64c x 72p x2 = 9216
static constexpr int WT3 = WT2 + 9216;             // 32c x 72p x2 = 4608
static constexpr int WT4 = WT3 + 4608;             // 32c x 40p x2 = 2560
static constexpr int WT5 = WT4 + 2560;             // 16c x 40p x2 = 1280
static constexpr int WT_TOT = WT5 + 1280;

static __device__ __forceinline__ void prep_f16(const float* __restrict__ W,
                                                int FIN, int FOUT, int KP,
                                                int PITCH, int NCT,
                                                short* __restrict__ dst, int t) {
    const int WCNT = NCT * 16 * PITCH;
    for (int li = t; li < NCT * 16 * KP; li += 256) {
        const int c = li / KP, k = li - c * KP;
        float f = (c < FOUT && k < FIN) ? W[k * FOUT + c] : 0.f;
        __half hh = __float2half_rn(f);
        __half hl = __float2half_rn(f - __half2float(hh));
        dst[c * PITCH + k] = __half_as_short(hh);
        dst[WCNT + c * PITCH + k] = __half_as_short(hl);
    }
}

__global__ void k_wprep(const float* __restrict__ W0, const float* __restrict__ W1,
                        const float* __restrict__ W2, const float* __restrict__ W3,
                        const float* __restrict__ W4, short* __restrict__ wt) {
    const int t = threadIdx.x;
    const int blk = blockIdx.x;
    if (blk < 2) {
        // layer-1 bf16 split (unchanged layout), halved across blocks 0,1
#pragma unroll
        for (int i = 0; i < 16; ++i) {
            const int li = t + 256 * (16 * blk + i);   // 0..8191
            const int c = li >> 7, k = li & 127;
            float f = (c < 50) ? W0[k * 50 + c] : 0.f;
            unsigned short hb = bf16rn(f);
            float hf = __uint_as_float((unsigned)hb << 16);
            unsigned short lb = bf16rn(f - hf);
            const int off = c * 128 + (k ^ ((c & 7) << 3));
            wt[off] = (short)hb;
            wt[8192 + off] = (short)lb;
        }
    } else if (blk == 2) prep_f16(W1, 50, 50, 64, 72, 4, wt + WT2, t);
    else if (blk == 3)   prep_f16(W2, 50, 30, 64, 72, 2, wt + WT3, t);
    else if (blk == 4)   prep_f16(W3, 30, 30, 32, 40, 2, wt + WT4, t);
    else                 prep_f16(W4, 30, 10, 32, 40, 1, wt + WT5, t);
}

// ---------------- layer 1: fp32 X, bf16 split MFMA (round-22, verified) ---

__global__ __launch_bounds__(256, 4) void k_matmul_f(const float* __restrict__ X,
                                                     const short* __restrict__ wt,
                                                     __half* __restrict__ H) {
    __shared__ short lds[2 * 64 * 128];           // Wt hi | lo, pre-swizzled, 32 KB
    const int t = threadIdx.x;
    {
        const int4* src = (const int4*)wt;
        int4* dst = (int4*)lds;
#pragma unroll
        for (int j = 0; j < 8; ++j) dst[j * 256 + t] = src[j * 256 + t];
    }
    const int w = t >> 6;
    const int lane = t & 63;
    const int lr = lane & 15;
    const int kg = lane >> 4;
    const int row = blockIdx.x * 64 + 16 * w + lr;
    const float* xr = X + (size_t)(row < NN ? row : NN - 1) * 128 + kg * 8;

    float4 xa[4][2];
#pragma unroll
    for (int kb = 0; kb < 4; ++kb) {
        xa[kb][0] = *(const float4*)(xr + kb * 32);
        xa[kb][1] = *(const float4*)(xr + kb * 32 + 4);
    }
    __syncthreads();

    f32x4v acc[4];
#pragma unroll
    for (int ct = 0; ct < 4; ++ct) acc[ct] = (f32x4v){0.f, 0.f, 0.f, 0.f};

#pragma unroll
    for (int kb = 0; kb < 4; ++kb) {
        s16x8 ah, al;
        const unsigned* xu = (const unsigned*)&xa[kb][0];
#pragma unroll
        for (int e = 0; e < 8; ++e) {
            const unsigned u = xu[e];
            const float lo = __uint_as_float(u) - __uint_as_float(u & 0xFFFF0000u);
            ah[e] = (short)(u >> 16);
            al[e] = (short)(__float_as_uint(lo) >> 16);
        }
        const int kf = kb * 32 + kg * 8;
        s16x8 bh[4], bl[4];
#pragma unroll
        for (int ct = 0; ct < 4; ++ct) {
            const int bc = ct * 16 + lr;
            const int ko = bc * 128 + (kf ^ ((bc & 7) << 3));
            bh[ct] = *(const s16x8*)&lds[ko];
            bl[ct] = *(const s16x8*)&lds[8192 + ko];
        }
#pragma unroll
        for (int ct = 0; ct < 4; ++ct)
            acc[ct] = __builtin_amdgcn_mfma_f32_16x16x32_bf16(ah, bh[ct], acc[ct], 0, 0, 0);
#pragma unroll
        for (int ct = 0; ct < 4; ++ct)
            acc[ct] = __builtin_amdgcn_mfma_f32_16x16x32_bf16(ah, bl[ct], acc[ct], 0, 0, 0);
#pragma unroll
        for (int ct = 0; ct < 4; ++ct)
            acc[ct] = __builtin_amdgcn_mfma_f32_16x16x32_bf16(al, bh[ct], acc[ct], 0, 0, 0);
    }

    const int gr = blockIdx.x * 64 + 16 * w + kg * 4;
#pragma unroll
    for (int ct = 0; ct < 4; ++ct) {
        const int col = ct * 16 + lr;
        if (col < 50) {
#pragma unroll
            for (int rg = 0; rg < 4; ++rg) {
                const int orow = gr + rg;
                if (orow < NN)
                    H[(size_t)orow * 64 + col] = __float2half_rn(acc[ct][rg]);
            }
        }
    }
}

// ---------------- layers 2..5: fp16 X, fp16 hi/lo split MFMA --------------

template <int FIN, int KP, int PITCH, int SX, int FOUT, int NCT, int S>
__global__ __launch_bounds__(256, 4) void k_matmul_fh(const __half* __restrict__ X,
                                                      const short* __restrict__ wt,
                                                      __half* __restrict__ H) {
    constexpr int NKB = KP / 32;
    constexpr int WCNT = NCT * 16 * PITCH;         // shorts per hi (= per lo)
    __shared__ short lds[2 * WCNT];
    const int t = threadIdx.x;
    {
        const int4* src = (const int4*)wt;
        int4* dst = (int4*)lds;
        constexpr int NI = (2 * WCNT) / 8;
        for (int j = t; j < NI; j += 256) dst[j] = src[j];
    }
    const int w = t >> 6;
    const int lane = t & 63;
    const int lr = lane & 15;
    const int kg = lane >> 4;
    const int row = blockIdx.x * 64 + 16 * w + lr;
    const __half* xr = X + (size_t)(row < NN ? row : NN - 1) * SX + kg * 8;

    int4 xa[NKB];
#pragma unroll
    for (int kb = 0; kb < NKB; ++kb) xa[kb] = *(const int4*)(xr + kb * 32);
    __syncthreads();

    f32x4v acc[NCT];
#pragma unroll
    for (int ct = 0; ct < NCT; ++ct) acc[ct] = (f32x4v){0.f, 0.f, 0.f, 0.f};

#pragma unroll
    for (int kb = 0; kb < NKB; ++kb) {
        f16x8 a = *(const f16x8*)&xa[kb];
        const int kf = kb * 32 + kg * 8;
#pragma unroll
        for (int ct = 0; ct < NCT; ++ct) {
            const int c = ct * 16 + lr;
            f16x8 bh = *(const f16x8*)&lds[c * PITCH + kf];
            f16x8 bl = *(const f16x8*)&lds[WCNT + c * PITCH + kf];
            acc[ct] = __builtin_amdgcn_mfma_f32_16x16x32_f16(a, bh, acc[ct], 0, 0, 0);
            acc[ct] = __builtin_amdgcn_mfma_f32_16x16x32_f16(a, bl, acc[ct], 0, 0, 0);
        }
    }

    const int gr = blockIdx.x * 64 + 16 * w + kg * 4;
#pragma unroll
    for (int ct = 0; ct < NCT; ++ct) {
        const int col = ct * 16 + lr;
        if (col < FOUT) {
#pragma unroll
            for (int rg = 0; rg < 4; ++rg) {
                const int orow = gr + rg;
                if (orow < NN)
                    H[(size_t)orow * S + col] = __float2half_rn(acc[ct][rg]);
            }
        }
    }
}

// ---------------- layer 6 (10 -> 10, VALU) and layer 7 (10 -> 1) ----------

template <int FIN, int SX, int FOUT, int S, int NSPL>
__global__ __launch_bounds__(256, 2) void k_matmul_h(const __half* __restrict__ X,
                                                     const float* __restrict__ W,
                                                     __half* __restrict__ H) {
    constexpr int FC = FOUT / NSPL;
    constexpr int NCH = (FIN + 7) / 8;
    const int node = blockIdx.x * 256 + threadIdx.x;
    const int ch = blockIdx.y;                 // SGPR by construction
    if (node >= NN) return;
    const __half* xr = X + (size_t)node * SX;
    int4 raw[NCH];
#pragma unroll
    for (int c = 0; c < NCH; ++c) raw[c] = *(const int4*)(xr + 8 * c);
    float acc[FC];
#pragma unroll
    for (int j = 0; j < FC; ++j) acc[j] = 0.0f;
#pragma unroll
    for (int c = 0; c < NCH; ++c) {
        const __half2* hp = (const __half2*)&raw[c];
        const int lim = (FIN - 8 * c < 8) ? FIN - 8 * c : 8;  // folds post-unroll
#pragma unroll
        for (int kk = 0; kk < 8; ++kk) {
            if (kk < lim) {
                __half2 pair = hp[kk >> 1];
                float xv = (kk & 1) ? __high2float(pair) : __low2float(pair);
                const float* wrow = W + (8 * c + kk) * FOUT + ch * FC;
#pragma unroll
                for (int j = 0; j < FC; ++j) acc[j] = fmaf(xv, wrow[j], acc[j]);
            }
        }
    }
    __half* hr = H + (size_t)node * S + ch * FC;
#pragma unroll
    for (int j = 0; j < FC; ++j) hr[j] = __float2half_rn(acc[j]);
}

__global__ void k_matmul_1h(const __half* __restrict__ X, const float* __restrict__ W,
                            float* __restrict__ H) {
    int i = blockIdx.x * blockDim.x + threadIdx.x;
    if (i >= NN) return;
    const __half* xr = X + (size_t)i * 16;
    int4 r0 = *(const int4*)xr;                  // halfs 0..7
    __half2 r1 = *(const __half2*)(xr + 8);      // halfs 8,9
    const __half2* hp = (const __half2*)&r0;
    float acc = 0.0f;
#pragma unroll
    for (int q = 0; q < 4; ++q) {
        acc = fmaf(__low2float(hp[q]), W[2 * q], acc);
        acc = fmaf(__high2float(hp[q]), W[2 * q + 1], acc);
    }
    acc = fmaf(__low2float(r1), W[8], acc);
    acc = fmaf(__high2float(r1), W[9], acc);
    H[i] = acc;
}

// ---------------- CSR pull aggregation + fused epilogue (fp16 H) ----------
// 8-edge batches (r24); nodes processed in degree-sorted order via perm[]
// so each wave's node-groups have similar degree (divergence ~= 0).
// Pad half2s beyond R zeroed (MFMA K-pad correctness).

static __device__ __forceinline__ int2 nt_load2(const int2* p) {
    unsigned long long raw = __builtin_nontemporal_load((const unsigned long long*)p);
    return make_int2((int)(raw & 0xFFFFFFFFull), (int)(raw >> 32));
}

template <int F, int SH, int SA, int LPN, bool RELU>
__global__ __launch_bounds__(256) void k_agg2(const int* __restrict__ offs,
                                              const int* __restrict__ perm,
                                              const int2* __restrict__ csw,
                                              const __half2* __restrict__ H,
                                              const float* __restrict__ dinv,
                                              const float* __restrict__ b,
                                              __half* __restrict__ O) {
    constexpr int R = F / 2;               // real half2 count per row
    int t = blockIdx.x * blockDim.x + threadIdx.x;
    int gidx = t / LPN;
    int f = t - gidx * LPN;
    if (gidx >= NN) return;
    const int g = perm[gidx];              // degree-sorted node id
    const int q0 = 4 * f;                  // first half2 this lane owns
    __half2* orow = (__half2*)(O + (size_t)g * SA) + q0;
    if (q0 >= R) {                         // pad-only lane: zero the pad
        const __half2 z = __floats2half2_rn(0.f, 0.f);
#pragma unroll
        for (int c = 0; c < 4; ++c)
            if (q0 + c < SA / 2) orow[c] = z;
        return;
    }
    int p = offs[g];
    const int pe = offs[g + 1];
    const int pl = pe - 1;

    float2 acc[4];
#pragma unroll
    for (int c = 0; c < 4; ++c) acc[c] = make_float2(0.f, 0.f);

    for (; p < pe; p += 8) {
        int2 e[8];
#pragma unroll
        for (int i = 0; i < 8; ++i) e[i] = nt_load2(csw + min(p + i, pl));
        __half2 h[8][4];
#pragma unroll
        for (int i = 0; i < 8; ++i)
            *(int4*)h[i] = *(const int4*)(H + (size_t)e[i].x * SH + q0);
#pragma unroll
        for (int i = 0; i < 8; ++i) {
            float w = (p + i < pe) ? __int_as_float(e[i].y) : 0.0f;
#pragma unroll
            for (int c = 0; c < 4; ++c) {
                acc[c].x = fmaf(__low2float(h[i][c]), w, acc[c].x);
                acc[c].y = fmaf(__high2float(h[i][c]), w, acc[c].y);
            }
        }
    }

    float di = dinv[g];
    float d2 = di * di;
    __half2 hs[4];
    *(int4*)hs = *(const int4*)(H + (size_t)g * SH + q0);
#pragma unroll
    for (int c = 0; c < 4; ++c) {
        if (q0 + c < R) {
            float vx = acc[c].x + fmaf(__low2float(hs[c]), d2, b[2 * (q0 + c)]);
            float vy = acc[c].y + fmaf(__high2float(hs[c]), d2, b[2 * (q0 + c) + 1]);
            if (RELU) { vx = fmaxf(vx, 0.f); vy = fmaxf(vy, 0.f); }
            orow[c] = __floats2half2_rn(vx, vy);
        } else if (q0 + c < SA / 2) {
            orow[c] = __floats2half2_rn(0.f, 0.f);   // zero pad tail
        }
    }
}

// F=1 aggregation (final layer, fp32 H): 8-wide predicated, degree-sorted.
__global__ void k_agg1(const int* __restrict__ offs, const int* __restrict__ perm,
                       const int2* __restrict__ csw,
                       const float* __restrict__ H, const float* __restrict__ dinv,
                       const float* __restrict__ b, float* __restrict__ O) {
    int gi = blockIdx.x * blockDim.x + threadIdx.x;
    if (gi >= NN) return;
    const int g = perm[gi];
    int p = offs[g];
    const int pe = offs[g + 1];
    const int pl = pe - 1;
    float a[8];
#pragma unroll
    for (int i = 0; i < 8; ++i) a[i] = 0.f;
    for (; p < pe; p += 8) {
        int2 e[8];
#pragma unroll
        for (int i = 0; i < 8; ++i) e[i] = nt_load2(csw + min(p + i, pl));
        float hv[8];
#pragma unroll
        for (int i = 0; i < 8; ++i) hv[i] = H[e[i].x];
#pragma unroll
        for (int i = 0; i < 8; ++i) {
            float w = (p + i < pe) ? __int_as_float(e[i].y) : 0.f;
            a[i] = fmaf(hv[i], w, a[i]);
        }
    }
    float di = dinv[g];
    float s = ((a[0] + a[1]) + (a[2] + a[3])) + ((a[4] + a[5]) + (a[6] + a[7]));
    O[g] = s + fmaf(H[g], di * di, b[0]);
}

// ---------------- launch ----------------

static inline size_t alignup(size_t x) { return (x + 255) & ~(size_t)255; }

extern "C" void kernel_launch(void* const* d_in, const int* in_sizes, int n_in,
                              void* d_out, int out_size, void* d_ws, size_t ws_size,
                              hipStream_t stream) {
    const float* x  = (const float*)d_in[0];
    const int*   ei = (const int*)d_in[1];
    const float* ew = (const float*)d_in[2];
    const float* Wp[7];
    const float* Bp[7];
    for (int l = 0; l < 7; ++l) {
        Wp[l] = (const float*)d_in[3 + 2 * l];
        Bp[l] = (const float*)d_in[4 + 2 * l];
    }
    const int* row = ei;       // source
    const int* col = ei + NE;  // destination

    // workspace carve (~70 MB); Hb/Aa/Ab fp16, stride <= 64 halfs
    char* ws = (char*)d_ws;
    float* dinv  = (float*)ws;  ws += alignup((size_t)NN * 4);
    char*  Hb    = ws;          ws += alignup((size_t)NN * 64 * 2);
    char*  Aa    = ws;          ws += alignup((size_t)NN * 64 * 2);
    char*  Ab    = ws;          ws += alignup((size_t)NN * 64 * 2);
    int*   offs  = (int*)ws;    ws += alignup((size_t)(NN + 1) * 4);
    int*   counts= (int*)ws;    ws += alignup((size_t)NBUK * EB * 4);
    int*   btot  = (int*)ws;    ws += alignup((size_t)NBUK * 4);
    int*   bstart= (int*)ws;    ws += alignup((size_t)(NBUK + 1) * 4);
    int2*  stg   = (int2*)ws;   ws += alignup((size_t)NE * 8);
    int2*  csw   = (int2*)ws;   ws += alignup((size_t)NE * 8);
    short* wt    = (short*)ws;  ws += alignup((size_t)WT_TOT * 2);
    int*   scnt  = (int*)ws;    ws += alignup((size_t)64 * SNB * 4);
    int*   stot  = (int*)ws;    ws += alignup((size_t)64 * 4);
    int*   sbst  = (int*)ws;    ws += alignup((size_t)64 * 4);
    int*   perm  = (int*)ws;    ws += alignup((size_t)NN * 4);

    const int gN = (NN + 255) / 256;
    const int gM = (NN + 63) / 64;     // 64-row MFMA tiles

    // W prep (6 small blocks) + CSR build — no global atomics
    k_wprep<<<6, 256, 0, stream>>>(Wp[0], Wp[1], Wp[2], Wp[3], Wp[4], wt);
    k_hist0<<<EB, 256, 0, stream>>>(col, counts);
    k_scanA<<<NBUK, 256, 0, stream>>>(counts, btot);
    k_scanB<<<1, 256, 0, stream>>>(btot, bstart);
    k_A1<<<EB, 256, 0, stream>>>(row, col, ew, counts, bstart, stg);
    k_bdeg<<<NBUK, 256, 0, stream>>>(bstart, stg, dinv);
    k_place<<<NBUK, 512, 0, stream>>>(bstart, stg, dinv, offs, csw);
    // degree-sorted permutation (4 tiny kernels, same bucket-major pattern)
    k_shist<<<SNB, 256, 0, stream>>>(offs, scnt);
    k_sscanA<<<64, 256, 0, stream>>>(scnt, stot);
    k_sscanB<<<1, 64, 0, stream>>>(stot, sbst);
    k_splace<<<SNB, 256, 0, stream>>>(offs, scnt, sbst, perm);

#define AGG(FOUT, S, LPN, RELU, OUT, LIDX)                                                  \
    k_agg2<FOUT, (S) / 2, S, LPN, RELU>                                                     \
        <<<((size_t)NN * (LPN) + 255) / 256, 256, 0, stream>>>(                             \
            offs, perm, csw, (const __half2*)Hb, dinv, Bp[LIDX], (__half*)(OUT))

    // layer 1: fp32 x input, bf16 split MFMA (W pre-staged, X direct)
    k_matmul_f<<<gM, 256, 0, stream>>>(x, wt, (__half*)Hb);
    AGG(50, 64, 8, true, Aa, 0);
    // layers 2..5: fp16 MFMA (hi/lo split W)
    k_matmul_fh<50, 64, 72, 64, 50, 4, 64><<<gM, 256, 0, stream>>>((const __half*)Aa, wt + WT2, (__half*)Hb);
    AGG(50, 64, 8, true, Ab, 1);
    k_matmul_fh<50, 64, 72, 64, 30, 2, 32><<<gM, 256, 0, stream>>>((const __half*)Ab, wt + WT3, (__half*)Hb);
    AGG(30, 32, 4, true, Aa, 2);
    k_matmul_fh<30, 32, 40, 32, 30, 2, 32><<<gM, 256, 0, stream>>>((const __half*)Aa, wt + WT4, (__half*)Hb);
    AGG(30, 32, 4, true, Ab, 3);
    k_matmul_fh<30, 32, 40, 32, 10, 1, 16><<<gM, 256, 0, stream>>>((const __half*)Ab, wt + WT5, (__half*)Hb);
    AGG(10, 16, 2, true, Aa, 4);
    // layer 6: 10 -> 10 VALU (wrong shape for K>=32 MFMA fragments)
    k_matmul_h<10, 16, 10, 16, 1><<<dim3(gN, 1), 256, 0, stream>>>((const __half*)Aa, Wp[5], (__half*)Hb);
    AGG(10, 16, 2, true, Ab, 5);
#undef AGG

    // layer 7: 10 -> 1, no relu, fp32 H, fp32 output
    k_matmul_1h<<<gN, 256, 0, stream>>>((const __half*)Ab, Wp[6], (float*)Hb);
    k_agg1<<<gN, 256, 0, stream>>>(offs, perm, csw, (const float*)Hb, dinv, Bp[6],
                                   (float*)d_out);
}

// Round 11
// 427.755 us; speedup vs baseline: 1.0396x; 1.0396x over previous
//
#include <hip/hip_runtime.h>
#include <hip/hip_fp16.h>

// GCN, 7 layers: h = relu(Â (h W) + b), Â = D^-1/2 (A + I) D^-1/2.
// Round 26: revert round-25's degree-sort (418.4 -> 444.7 REGRESSION: perm
// scattered the agg writes/self-reads — coalescing loss > divergence gain,
// +sort overhead ~10us; divergence is absorbed by TLP). Back to the exact
// round-24 (418.4us) config with ONE change: agg batch depth 8 -> 16
// (16 csw loads + 16 H gathers in flight per lane). r24 proved the aggs are
// latency-bound and respond to ILP depth (4->8 = -23.6us); at mean degree
// ~16 a 16-deep batch turns 2 serialized load rounds into 1. VGPR ~120,
// still >=4 waves/SIMD, no spill risk (acc is small; r18's spill was the
// 50-deep acc + W streaming combo).

static constexpr int NN = 100000;
static constexpr int NE = 1600000;
static constexpr int BKL = 9;                      // 512 nodes per bucket
static constexpr int NBUK = (NN + 511) >> BKL;     // 196 buckets
static constexpr int EPT = 8;                      // edges per thread (hist/A1)
static constexpr int EB = (NE + 2047) / 2048;      // 782 edge blocks

// ---------------- 1. bucket histogram (LDS only) ----------------

__global__ __launch_bounds__(256) void k_hist0(const int* __restrict__ col,
                                               int* __restrict__ counts) {
    __shared__ int lh[NBUK];
    for (int j = threadIdx.x; j < NBUK; j += 256) lh[j] = 0;
    __syncthreads();
    int base = blockIdx.x * 2048;
#pragma unroll
    for (int k = 0; k < EPT; ++k) {
        int e = base + k * 256 + threadIdx.x;
        if (e < NE) atomicAdd(&lh[col[e] >> BKL], 1);
    }
    __syncthreads();
    for (int j = threadIdx.x; j < NBUK; j += 256)
        counts[j * EB + blockIdx.x] = lh[j];  // bucket-major
}

// ---------------- 2a. per-bucket scan (196 parallel blocks) ----------------

__global__ __launch_bounds__(256) void k_scanA(int* __restrict__ counts,
                                               int* __restrict__ btot) {
    __shared__ int lds[256];
    const int b = blockIdx.x;
    const int t = threadIdx.x;
    int* c = counts + (size_t)b * EB;
    constexpr int PER = (EB + 255) / 256;  // 4
    int v[PER];
    int s = 0;
#pragma unroll
    for (int k = 0; k < PER; ++k) {
        int idx = t * PER + k;
        v[k] = (idx < EB) ? c[idx] : 0;
        s += v[k];
    }
    lds[t] = s;
    __syncthreads();
    for (int off = 1; off < 256; off <<= 1) {
        int u = (t >= off) ? lds[t - off] : 0;
        __syncthreads();
        lds[t] += u;
        __syncthreads();
    }
    int run = lds[t] - s;
#pragma unroll
    for (int k = 0; k < PER; ++k) {
        int idx = t * PER + k;
        if (idx < EB) { c[idx] = run; run += v[k]; }
    }
    if (t == 255) btot[b] = lds[255];
}

// ---------------- 2b. scan of 196 bucket totals -> bstart ----------------

__global__ void k_scanB(const int* __restrict__ btot, int* __restrict__ bstart) {
    __shared__ int lds[256];
    int t = threadIdx.x;
    int v = (t < NBUK) ? btot[t] : 0;
    lds[t] = v;
    __syncthreads();
    for (int off = 1; off < 256; off <<= 1) {
        int u = (t >= off) ? lds[t - off] : 0;
        __syncthreads();
        lds[t] += u;
        __syncthreads();
    }
    if (t < NBUK) bstart[t] = lds[t] - v;  // exclusive
    if (t == 0) bstart[NBUK] = NE;
}

// ---------------- 3. stage records, bucket-grouped (LDS cursors) ----------

__global__ __launch_bounds__(256) void k_A1(const int* __restrict__ row,
                                            const int* __restrict__ col,
                                            const float* __restrict__ ew,
                                            const int* __restrict__ counts,
                                            const int* __restrict__ bstart,
                                            int2* __restrict__ stg) {
    __shared__ int cur[NBUK];
    for (int j = threadIdx.x; j < NBUK; j += 256)
        cur[j] = bstart[j] + counts[j * EB + blockIdx.x];
    __syncthreads();
    int base = blockIdx.x * 2048;
#pragma unroll
    for (int k = 0; k < EPT; ++k) {
        int e = base + k * 256 + threadIdx.x;
        if (e < NE) {
            int c = col[e], r = row[e];
            int pos = atomicAdd(&cur[c >> BKL], 1);  // LDS atomic
            stg[pos] = make_int2(((c & 511) << 17) | r, __float_as_int(ew[e]));
        }
    }
}

// ---------------- 4. per-bucket degree -> dinv (plain stores) ----------

__global__ __launch_bounds__(256) void k_bdeg(const int* __restrict__ bstart,
                                              const int2* __restrict__ stg,
                                              float* __restrict__ dinv) {
    __shared__ float sdeg[512];
    const int b = blockIdx.x;
    for (int j = threadIdx.x; j < 512; j += 256) sdeg[j] = 0.0f;
    __syncthreads();
    const int s = bstart[b], e = bstart[b + 1];
    for (int p = s + threadIdx.x; p < e; p += 256) {
        int2 rec = stg[p];
        atomicAdd(&sdeg[rec.x >> 17], __int_as_float(rec.y));
    }
    __syncthreads();
    for (int j = threadIdx.x; j < 512; j += 256) {
        int idx = (b << BKL) + j;
        if (idx < NN) dinv[idx] = rsqrtf(sdeg[j] + 1.0f);  // +1 self-loop
    }
}

// ---------------- 5. per-bucket placement: offs + csw (LDS scan) ----------

__global__ __launch_bounds__(512) void k_place(const int* __restrict__ bstart,
                                               const int2* __restrict__ stg,
                                               const float* __restrict__ dinv,
                                               int* __restrict__ offs,
                                               int2* __restrict__ csw) {
    __shared__ int lcnt[512];
    __shared__ int cur[512];
    const int b = blockIdx.x;
    const int t = threadIdx.x;
    lcnt[t] = 0;
    __syncthreads();
    const int s = bstart[b], e = bstart[b + 1];
    for (int p = s + t; p < e; p += 512)
        atomicAdd(&lcnt[stg[p].x >> 17], 1);
    __syncthreads();
    int v = lcnt[t];
    for (int off = 1; off < 512; off <<= 1) {   // inclusive Hillis-Steele
        int u = (t >= off) ? lcnt[t - off] : 0;
        __syncthreads();
        lcnt[t] += u;
        __syncthreads();
    }
    int excl = lcnt[t] - v;
    int idx = (b << BKL) + t;
    if (idx <= NN) offs[idx] = s + excl;        // covers offs[NN] exactly once
    cur[t] = s + excl;
    __syncthreads();
    for (int p = s + t; p < e; p += 512) {
        int2 rec = stg[p];
        int cl = rec.x >> 17;
        int r = rec.x & 0x1FFFF;
        float nw = dinv[r] * __int_as_float(rec.y) * dinv[(b << BKL) + cl];
        int slot = atomicAdd(&cur[cl], 1);      // LDS atomic
        csw[slot] = make_int2(r, __float_as_int(nw));
    }
}

// ---------------- weight prep (6 small blocks, runs once per graph) -------

typedef short s16x8 __attribute__((ext_vector_type(8)));
typedef float f32x4v __attribute__((ext_vector_type(4)));
typedef _Float16 f16x8 __attribute__((ext_vector_type(8)));

static __device__ __forceinline__ unsigned short bf16rn(float f) {
    unsigned u = __float_as_uint(f);
    return (unsigned short)((u + 0x7FFFu + ((u >> 16) & 1u)) >> 16);
}

// wt layout (shorts):
//  [0, 16384)      layer-1 bf16 hi|lo, transposed, XOR-swizzled (round-22)
//  [WT2..) fp16 hi|lo transposed tiles, pitch-padded, for layers 2..5
static constexpr int WT2 = 16384;                  // 64c x 72p x2 = 9216
static constexpr int WT3 = WT2 + 9216;             // 32c x 72p x2 = 4608
static constexpr int WT4 = WT3 + 4608;             // 32c x 40p x2 = 2560
static constexpr int WT5 = WT4 + 2560;             // 16c x 40p x2 = 1280
static constexpr int WT_TOT = WT5 + 1280;

static __device__ __forceinline__ void prep_f16(const float* __restrict__ W,
                                                int FIN, int FOUT, int KP,
                                                int PITCH, int NCT,
                                                short* __restrict__ dst, int t) {
    const int WCNT = NCT * 16 * PITCH;
    for (int li = t; li < NCT * 16 * KP; li += 256) {
        const int c = li / KP, k = li - c * KP;
        float f = (c < FOUT && k < FIN) ? W[k * FOUT + c] : 0.f;
        __half hh = __float2half_rn(f);
        __half hl = __float2half_rn(f - __half2float(hh));
        dst[c * PITCH + k] = __half_as_short(hh);
        dst[WCNT + c * PITCH + k] = __half_as_short(hl);
    }
}

__global__ void k_wprep(const float* __restrict__ W0, const float* __restrict__ W1,
                        const float* __restrict__ W2, const float* __restrict__ W3,
                        const float* __restrict__ W4, short* __restrict__ wt) {
    const int t = threadIdx.x;
    const int blk = blockIdx.x;
    if (blk < 2) {
        // layer-1 bf16 split (unchanged layout), halved across blocks 0,1
#pragma unroll
        for (int i = 0; i < 16; ++i) {
            const int li = t + 256 * (16 * blk + i);   // 0..8191
            const int c = li >> 7, k = li & 127;
            float f = (c < 50) ? W0[k * 50 + c] : 0.f;
            unsigned short hb = bf16rn(f);
            float hf = __uint_as_float((unsigned)hb << 16);
            unsigned short lb = bf16rn(f - hf);
            const int off = c * 128 + (k ^ ((c & 7) << 3));
            wt[off] = (short)hb;
            wt[8192 + off] = (short)lb;
        }
    } else if (blk == 2) prep_f16(W1, 50, 50, 64, 72, 4, wt + WT2, t);
    else if (blk == 3)   prep_f16(W2, 50, 30, 64, 72, 2, wt + WT3, t);
    else if (blk == 4)   prep_f16(W3, 30, 30, 32, 40, 2, wt + WT4, t);
    else                 prep_f16(W4, 30, 10, 32, 40, 1, wt + WT5, t);
}

// ---------------- layer 1: fp32 X, bf16 split MFMA (round-22, verified) ---

__global__ __launch_bounds__(256, 4) void k_matmul_f(const float* __restrict__ X,
                                                     const short* __restrict__ wt,
                                                     __half* __restrict__ H) {
    __shared__ short lds[2 * 64 * 128];           // Wt hi | lo, pre-swizzled, 32 KB
    const int t = threadIdx.x;
    {
        const int4* src = (const int4*)wt;
        int4* dst = (int4*)lds;
#pragma unroll
        for (int j = 0; j < 8; ++j) dst[j * 256 + t] = src[j * 256 + t];
    }
    const int w = t >> 6;
    const int lane = t & 63;
    const int lr = lane & 15;
    const int kg = lane >> 4;
    const int row = blockIdx.x * 64 + 16 * w + lr;
    const float* xr = X + (size_t)(row < NN ? row : NN - 1) * 128 + kg * 8;

    float4 xa[4][2];
#pragma unroll
    for (int kb = 0; kb < 4; ++kb) {
        xa[kb][0] = *(const float4*)(xr + kb * 32);
        xa[kb][1] = *(const float4*)(xr + kb * 32 + 4);
    }
    __syncthreads();

    f32x4v acc[4];
#pragma unroll
    for (int ct = 0; ct < 4; ++ct) acc[ct] = (f32x4v){0.f, 0.f, 0.f, 0.f};

#pragma unroll
    for (int kb = 0; kb < 4; ++kb) {
        s16x8 ah, al;
        const unsigned* xu = (const unsigned*)&xa[kb][0];
#pragma unroll
        for (int e = 0; e < 8; ++e) {
            const unsigned u = xu[e];
            const float lo = __uint_as_float(u) - __uint_as_float(u & 0xFFFF0000u);
            ah[e] = (short)(u >> 16);
            al[e] = (short)(__float_as_uint(lo) >> 16);
        }
        const int kf = kb * 32 + kg * 8;
        s16x8 bh[4], bl[4];
#pragma unroll
        for (int ct = 0; ct < 4; ++ct) {
            const int bc = ct * 16 + lr;
            const int ko = bc * 128 + (kf ^ ((bc & 7) << 3));
            bh[ct] = *(const s16x8*)&lds[ko];
            bl[ct] = *(const s16x8*)&lds[8192 + ko];
        }
#pragma unroll
        for (int ct = 0; ct < 4; ++ct)
            acc[ct] = __builtin_amdgcn_mfma_f32_16x16x32_bf16(ah, bh[ct], acc[ct], 0, 0, 0);
#pragma unroll
        for (int ct = 0; ct < 4; ++ct)
            acc[ct] = __builtin_amdgcn_mfma_f32_16x16x32_bf16(ah, bl[ct], acc[ct], 0, 0, 0);
#pragma unroll
        for (int ct = 0; ct < 4; ++ct)
            acc[ct] = __builtin_amdgcn_mfma_f32_16x16x32_bf16(al, bh[ct], acc[ct], 0, 0, 0);
    }

    const int gr = blockIdx.x * 64 + 16 * w + kg * 4;
#pragma unroll
    for (int ct = 0; ct < 4; ++ct) {
        const int col = ct * 16 + lr;
        if (col < 50) {
#pragma unroll
            for (int rg = 0; rg < 4; ++rg) {
                const int orow = gr + rg;
                if (orow < NN)
                    H[(size_t)orow * 64 + col] = __float2half_rn(acc[ct][rg]);
            }
        }
    }
}

// ---------------- layers 2..5: fp16 X, fp16 hi/lo split MFMA --------------

template <int FIN, int KP, int PITCH, int SX, int FOUT, int NCT, int S>
__global__ __launch_bounds__(256, 4) void k_matmul_fh(const __half* __restrict__ X,
                                                      const short* __restrict__ wt,
                                                      __half* __restrict__ H) {
    constexpr int NKB = KP / 32;
    constexpr int WCNT = NCT * 16 * PITCH;         // shorts per hi (= per lo)
    __shared__ short lds[2 * WCNT];
    const int t = threadIdx.x;
    {
        const int4* src = (const int4*)wt;
        int4* dst = (int4*)lds;
        constexpr int NI = (2 * WCNT) / 8;
        for (int j = t; j < NI; j += 256) dst[j] = src[j];
    }
    const int w = t >> 6;
    const int lane = t & 63;
    const int lr = lane & 15;
    const int kg = lane >> 4;
    const int row = blockIdx.x * 64 + 16 * w + lr;
    const __half* xr = X + (size_t)(row < NN ? row : NN - 1) * SX + kg * 8;

    int4 xa[NKB];
#pragma unroll
    for (int kb = 0; kb < NKB; ++kb) xa[kb] = *(const int4*)(xr + kb * 32);
    __syncthreads();

    f32x4v acc[NCT];
#pragma unroll
    for (int ct = 0; ct < NCT; ++ct) acc[ct] = (f32x4v){0.f, 0.f, 0.f, 0.f};

#pragma unroll
    for (int kb = 0; kb < NKB; ++kb) {
        f16x8 a = *(const f16x8*)&xa[kb];
        const int kf = kb * 32 + kg * 8;
#pragma unroll
        for (int ct = 0; ct < NCT; ++ct) {
            const int c = ct * 16 + lr;
            f16x8 bh = *(const f16x8*)&lds[c * PITCH + kf];
            f16x8 bl = *(const f16x8*)&lds[WCNT + c * PITCH + kf];
            acc[ct] = __builtin_amdgcn_mfma_f32_16x16x32_f16(a, bh, acc[ct], 0, 0, 0);
            acc[ct] = __builtin_amdgcn_mfma_f32_16x16x32_f16(a, bl, acc[ct], 0, 0, 0);
        }
    }

    const int gr = blockIdx.x * 64 + 16 * w + kg * 4;
#pragma unroll
    for (int ct = 0; ct < NCT; ++ct) {
        const int col = ct * 16 + lr;
        if (col < FOUT) {
#pragma unroll
            for (int rg = 0; rg < 4; ++rg) {
                const int orow = gr + rg;
                if (orow < NN)
                    H[(size_t)orow * S + col] = __float2half_rn(acc[ct][rg]);
            }
        }
    }
}

// ---------------- layer 6 (10 -> 10, VALU) and layer 7 (10 -> 1) ----------

template <int FIN, int SX, int FOUT, int S, int NSPL>
__global__ __launch_bounds__(256, 2) void k_matmul_h(const __half* __restrict__ X,
                                                     const float* __restrict__ W,
                                                     __half* __restrict__ H) {
    constexpr int FC = FOUT / NSPL;
    constexpr int NCH = (FIN + 7) / 8;
    const int node = blockIdx.x * 256 + threadIdx.x;
    const int ch = blockIdx.y;                 // SGPR by construction
    if (node >= NN) return;
    const __half* xr = X + (size_t)node * SX;
    int4 raw[NCH];
#pragma unroll
    for (int c = 0; c < NCH; ++c) raw[c] = *(const int4*)(xr + 8 * c);
    float acc[FC];
#pragma unroll
    for (int j = 0; j < FC; ++j) acc[j] = 0.0f;
#pragma unroll
    for (int c = 0; c < NCH; ++c) {
        const __half2* hp = (const __half2*)&raw[c];
        const int lim = (FIN - 8 * c < 8) ? FIN - 8 * c : 8;  // folds post-unroll
#pragma unroll
        for (int kk = 0; kk < 8; ++kk) {
            if (kk < lim) {
                __half2 pair = hp[kk >> 1];
                float xv = (kk & 1) ? __high2float(pair) : __low2float(pair);
                const float* wrow = W + (8 * c + kk) * FOUT + ch * FC;
#pragma unroll
                for (int j = 0; j < FC; ++j) acc[j] = fmaf(xv, wrow[j], acc[j]);
            }
        }
    }
    __half* hr = H + (size_t)node * S + ch * FC;
#pragma unroll
    for (int j = 0; j < FC; ++j) hr[j] = __float2half_rn(acc[j]);
}

__global__ void k_matmul_1h(const __half* __restrict__ X, const float* __restrict__ W,
                            float* __restrict__ H) {
    int i = blockIdx.x * blockDim.x + threadIdx.x;
    if (i >= NN) return;
    const __half* xr = X + (size_t)i * 16;
    int4 r0 = *(const int4*)xr;                  // halfs 0..7
    __half2 r1 = *(const __half2*)(xr + 8);      // halfs 8,9
    const __half2* hp = (const __half2*)&r0;
    float acc = 0.0f;
#pragma unroll
    for (int q = 0; q < 4; ++q) {
        acc = fmaf(__low2float(hp[q]), W[2 * q], acc);
        acc = fmaf(__high2float(hp[q]), W[2 * q + 1], acc);
    }
    acc = fmaf(__low2float(r1), W[8], acc);
    acc = fmaf(__high2float(r1), W[9], acc);
    H[i] = acc;
}

// ---------------- CSR pull aggregation + fused epilogue (fp16 H) ----------
// 16-edge batches: 16 record loads + 16 row gathers in flight per lane.
// Pad half2s beyond R zeroed (MFMA K-pad correctness).

static __device__ __forceinline__ int2 nt_load2(const int2* p) {
    unsigned long long raw = __builtin_nontemporal_load((const unsigned long long*)p);
    return make_int2((int)(raw & 0xFFFFFFFFull), (int)(raw >> 32));
}

template <int F, int SH, int SA, int LPN, bool RELU>
__global__ __launch_bounds__(256) void k_agg2(const int* __restrict__ offs,
                                              const int2* __restrict__ csw,
                                              const __half2* __restrict__ H,
                                              const float* __restrict__ dinv,
                                              const float* __restrict__ b,
                                              __half* __restrict__ O) {
    constexpr int R = F / 2;               // real half2 count per row
    constexpr int BD = 16;                 // batch depth (in-flight loads)
    int t = blockIdx.x * blockDim.x + threadIdx.x;
    int g = t / LPN;
    int f = t - g * LPN;
    if (g >= NN) return;
    const int q0 = 4 * f;                  // first half2 this lane owns
    __half2* orow = (__half2*)(O + (size_t)g * SA) + q0;
    if (q0 >= R) {                         // pad-only lane: zero the pad
        const __half2 z = __floats2half2_rn(0.f, 0.f);
#pragma unroll
        for (int c = 0; c < 4; ++c)
            if (q0 + c < SA / 2) orow[c] = z;
        return;
    }
    int p = offs[g];
    const int pe = offs[g + 1];
    const int pl = pe - 1;

    float2 acc[4];
#pragma unroll
    for (int c = 0; c < 4; ++c) acc[c] = make_float2(0.f, 0.f);

    for (; p < pe; p += BD) {
        int2 e[BD];
#pragma unroll
        for (int i = 0; i < BD; ++i) e[i] = nt_load2(csw + min(p + i, pl));
        __half2 h[BD][4];
#pragma unroll
        for (int i = 0; i < BD; ++i)
            *(int4*)h[i] = *(const int4*)(H + (size_t)e[i].x * SH + q0);
#pragma unroll
        for (int i = 0; i < BD; ++i) {
            float w = (p + i < pe) ? __int_as_float(e[i].y) : 0.0f;
#pragma unroll
            for (int c = 0; c < 4; ++c) {
                acc[c].x = fmaf(__low2float(h[i][c]), w, acc[c].x);
                acc[c].y = fmaf(__high2float(h[i][c]), w, acc[c].y);
            }
        }
    }

    float di = dinv[g];
    float d2 = di * di;
    __half2 hs[4];
    *(int4*)hs = *(const int4*)(H + (size_t)g * SH + q0);
#pragma unroll
    for (int c = 0; c < 4; ++c) {
        if (q0 + c < R) {
            float vx = acc[c].x + fmaf(__low2float(hs[c]), d2, b[2 * (q0 + c)]);
            float vy = acc[c].y + fmaf(__high2float(hs[c]), d2, b[2 * (q0 + c) + 1]);
            if (RELU) { vx = fmaxf(vx, 0.f); vy = fmaxf(vy, 0.f); }
            orow[c] = __floats2half2_rn(vx, vy);
        } else if (q0 + c < SA / 2) {
            orow[c] = __floats2half2_rn(0.f, 0.f);   // zero pad tail
        }
    }
}

// F=1 aggregation (final layer, fp32 H): 16-wide predicated batches.
__global__ void k_agg1(const int* __restrict__ offs, const int2* __restrict__ csw,
                       const float* __restrict__ H, const float* __restrict__ dinv,
                       const float* __restrict__ b, float* __restrict__ O) {
    constexpr int BD = 16;
    int g = blockIdx.x * blockDim.x + threadIdx.x;
    if (g >= NN) return;
    int p = offs[g];
    const int pe = offs[g + 1];
    const int pl = pe - 1;
    float a[BD];
#pragma unroll
    for (int i = 0; i < BD; ++i) a[i] = 0.f;
    for (; p < pe; p += BD) {
        int2 e[BD];
#pragma unroll
        for (int i = 0; i < BD; ++i) e[i] = nt_load2(csw + min(p + i, pl));
        float hv[BD];
#pragma unroll
        for (int i = 0; i < BD; ++i) hv[i] = H[e[i].x];
#pragma unroll
        for (int i = 0; i < BD; ++i) {
            float w = (p + i < pe) ? __int_as_float(e[i].y) : 0.f;
            a[i] = fmaf(hv[i], w, a[i]);
        }
    }
    float di = dinv[g];
    float s = 0.f;
#pragma unroll
    for (int i = 0; i < BD; ++i) s += a[i];
    O[g] = s + fmaf(H[g], di * di, b[0]);
}

// ---------------- launch ----------------

static inline size_t alignup(size_t x) { return (x + 255) & ~(size_t)255; }

extern "C" void kernel_launch(void* const* d_in, const int* in_sizes, int n_in,
                              void* d_out, int out_size, void* d_ws, size_t ws_size,
                              hipStream_t stream) {
    const float* x  = (const float*)d_in[0];
    const int*   ei = (const int*)d_in[1];
    const float* ew = (const float*)d_in[2];
    const float* Wp[7];
    const float* Bp[7];
    for (int l = 0; l < 7; ++l) {
        Wp[l] = (const float*)d_in[3 + 2 * l];
        Bp[l] = (const float*)d_in[4 + 2 * l];
    }
    const int* row = ei;       // source
    const int* col = ei + NE;  // destination

    // workspace carve (~70 MB); Hb/Aa/Ab fp16, stride <= 64 halfs
    char* ws = (char*)d_ws;
    float* dinv  = (float*)ws;  ws += alignup((size_t)NN * 4);
    char*  Hb    = ws;          ws += alignup((size_t)NN * 64 * 2);
    char*  Aa    = ws;          ws += alignup((size_t)NN * 64 * 2);
    char*  Ab    = ws;          ws += alignup((size_t)NN * 64 * 2);
    int*   offs  = (int*)ws;    ws += alignup((size_t)(NN + 1) * 4);
    int*   counts= (int*)ws;    ws += alignup((size_t)NBUK * EB * 4);
    int*   btot  = (int*)ws;    ws += alignup((size_t)NBUK * 4);
    int*   bstart= (int*)ws;    ws += alignup((size_t)(NBUK + 1) * 4);
    int2*  stg   = (int2*)ws;   ws += alignup((size_t)NE * 8);
    int2*  csw   = (int2*)ws;   ws += alignup((size_t)NE * 8);
    short* wt    = (short*)ws;  ws += alignup((size_t)WT_TOT * 2);

    const int gN = (NN + 255) / 256;
    const int gM = (NN + 63) / 64;     // 64-row MFMA tiles

    // W prep (6 small blocks) + CSR build — no global atomics
    k_wprep<<<6, 256, 0, stream>>>(Wp[0], Wp[1], Wp[2], Wp[3], Wp[4], wt);
    k_hist0<<<EB, 256, 0, stream>>>(col, counts);
    k_scanA<<<NBUK, 256, 0, stream>>>(counts, btot);
    k_scanB<<<1, 256, 0, stream>>>(btot, bstart);
    k_A1<<<EB, 256, 0, stream>>>(row, col, ew, counts, bstart, stg);
    k_bdeg<<<NBUK, 256, 0, stream>>>(bstart, stg, dinv);
    k_place<<<NBUK, 512, 0, stream>>>(bstart, stg, dinv, offs, csw);

#define AGG(FOUT, S, LPN, RELU, OUT, LIDX)                                                  \
    k_agg2<FOUT, (S) / 2, S, LPN, RELU>                                                     \
        <<<((size_t)NN * (LPN) + 255) / 256, 256, 0, stream>>>(                             \
            offs, csw, (const __half2*)Hb, dinv, Bp[LIDX], (__half*)(OUT))

    // layer 1: fp32 x input, bf16 split MFMA (W pre-staged, X direct)
    k_matmul_f<<<gM, 256, 0, stream>>>(x, wt, (__half*)Hb);
    AGG(50, 64, 8, true, Aa, 0);
    // layers 2..5: fp16 MFMA (hi/lo split W)
    k_matmul_fh<50, 64, 72, 64, 50, 4, 64><<<gM, 256, 0, stream>>>((const __half*)Aa, wt + WT2, (__half*)Hb);
    AGG(50, 64, 8, true, Ab, 1);
    k_matmul_fh<50, 64, 72, 64, 30, 2, 32><<<gM, 256, 0, stream>>>((const __half*)Ab, wt + WT3, (__half*)Hb);
    AGG(30, 32, 4, true, Aa, 2);
    k_matmul_fh<30, 32, 40, 32, 30, 2, 32><<<gM, 256, 0, stream>>>((const __half*)Aa, wt + WT4, (__half*)Hb);
    AGG(30, 32, 4, true, Ab, 3);
    k_matmul_fh<30, 32, 40, 32, 10, 1, 16><<<gM, 256, 0, stream>>>((const __half*)Ab, wt + WT5, (__half*)Hb);
    AGG(10, 16, 2, true, Aa, 4);
    // layer 6: 10 -> 10 VALU (wrong shape for K>=32 MFMA fragments)
    k_matmul_h<10, 16, 10, 16, 1><<<dim3(gN, 1), 256, 0, stream>>>((const __half*)Aa, Wp[5], (__half*)Hb);
    AGG(10, 16, 2, true, Ab, 5);
#undef AGG

    // layer 7: 10 -> 1, no relu, fp32 H, fp32 output
    k_matmul_1h<<<gN, 256, 0, stream>>>((const __half*)Ab, Wp[6], (float*)Hb);
    k_agg1<<<gN, 256, 0, stream>>>(offs, csw, (const float*)Hb, dinv, Bp[6],
                                   (float*)d_out);
}